// Round 2
// baseline (561.161 us; speedup 1.0000x reference)
//
#include <hip/hip_runtime.h>
#include <hip/hip_bf16.h>

#define PI_F 3.14159265f

// Flat index convention: state.reshape((2,)*16) => qubit q corresponds to
// flat bit j = 15 - q.  Circuit per layer (flat-bit gates):
//   Ry on all flat bits j (angle of qubit 15-j)
//   CNOT chain: (c=15,t=14),(14,13),...,(1,0),(0,15)
//   Rz on all flat bits (phase of qubit 15-j)
// Measurement: <Z_q> q=0,1,2  ->  flat bits 15,14,13.

__device__ __forceinline__ unsigned swz(unsigned l){ return l ^ ((l>>5)&31u); }

__device__ __forceinline__ void ry_pair(float2& A0, float2& A1, float c, float s){
    float2 a0=A0, a1=A1;
    A0 = make_float2(c*a0.x - s*a1.x, c*a0.y - s*a1.y);
    A1 = make_float2(s*a0.x + c*a1.x, s*a0.y + c*a1.y);
}

// ---------------- P1: generate full Ry1 product state + CN1(15->14),(14->13)
// Type B tiling: outer = f bits 10..12.  T3 regs: i bits {0,1}=f{0,1}, i bits{2,3,4}=f{13,14,15}, t=f bits 2..9.
__global__ __launch_bounds__(256) void k_gen(const float* __restrict__ xg,
                                             const float* __restrict__ pg,
                                             float2* __restrict__ st)
{
    __shared__ float cg[16], sg[16];
    const int tid = threadIdx.x;
    const int b = blockIdx.x >> 3;
    const unsigned outer = blockIdx.x & 7u;        // f bits 10..12
    if (tid < 16){
        int j = tid, q = 15 - j;
        float th = 0.5f*(xg[b*16+q]*PI_F + pg[q]);
        float s, c; __sincosf(th, &s, &c);
        cg[j]=c; sg[j]=s;
    }
    __syncthreads();
    const unsigned t = tid;
    float base = 1.0f;
    #pragma unroll
    for (int j=2;j<10;j++)  base *= ((t>>(j-2))&1u)     ? sg[j] : cg[j];
    #pragma unroll
    for (int j=10;j<13;j++) base *= ((outer>>(j-10))&1u) ? sg[j] : cg[j];
    float2 a[32];
    #pragma unroll
    for (int i=0;i<32;i++){
        float pr = base;
        pr *= (i&1)      ? sg[0]  : cg[0];
        pr *= ((i>>1)&1) ? sg[1]  : cg[1];
        pr *= ((i>>2)&1) ? sg[13] : cg[13];
        pr *= ((i>>3)&1) ? sg[14] : cg[14];
        pr *= ((i>>4)&1) ? sg[15] : cg[15];
        a[i] = make_float2(pr, 0.0f);
    }
    // CN1(15->14): control i bit4, target i bit3
    #pragma unroll
    for (int j=0;j<32;j++){ if (j&8) continue; if ((j>>4)&1){ float2 tm=a[j]; a[j]=a[j|8]; a[j|8]=tm; } }
    // CN1(14->13): control i bit3, target i bit2
    #pragma unroll
    for (int j=0;j<32;j++){ if (j&4) continue; if ((j>>3)&1){ float2 tm=a[j]; a[j]=a[j|4]; a[j|4]=tm; } }
    float2* sp = st + ((size_t)b<<16);
    #pragma unroll
    for (int u=0;u<8;u++){
        unsigned fb = (t<<2) | (outer<<10) | ((unsigned)u<<13);
        float4* d4 = (float4*)(sp + fb);
        d4[0]=make_float4(a[4*u+0].x,a[4*u+0].y,a[4*u+1].x,a[4*u+1].y);
        d4[1]=make_float4(a[4*u+2].x,a[4*u+2].y,a[4*u+3].x,a[4*u+3].y);
    }
}

// ---------------- Type-A pass (outer = f bits 13..15; local f bits 0..12)
// MODE 0: layer1 chain mid + Rz1(0..14) + Ry2(1..4)
// MODE 1: Ry2(10..12) + layer2 chain mid + Rz2(0..14) + Ry3(1..4)
// MODE 2: Ry3(10..12) + layer3 chain mid + measurement (CN3(0->15) folded, Rz3 dropped)
template<int MODE>
__global__ __launch_bounds__(256) void k_A(const float* __restrict__ xg,
                                           const float* __restrict__ pg,
                                           float2* __restrict__ st,
                                           float* __restrict__ outg)
{
    __shared__ float2 tile[8192];
    __shared__ float cP[16], sP[16], cN[16], sN[16], phz[16];
    __shared__ float red[4][3];
    const int tid = threadIdx.x;
    const int b = blockIdx.x >> 3;
    const unsigned outer = blockIdx.x & 7u;        // f bits 13..15
    const int prevoff = (MODE==1)? 32 : 64;        // Ry layer l   (unused MODE0)
    const int rzoff   = (MODE==0)? 16 : 48;        // Rz layer l   (unused MODE2)
    const int nxoff   = (MODE==0)? 32 : 64;        // Ry layer l+1 (unused MODE2)
    if (tid < 16){
        int j=tid, q=15-j;
        if (MODE>=1){ float th=0.5f*(xg[b*16+q]*PI_F + pg[prevoff+q]); float s,c; __sincosf(th,&s,&c); cP[j]=c; sP[j]=s; }
        if (MODE<=1){
            float th=0.5f*(xg[b*16+q]*PI_F + pg[nxoff+q]); float s,c; __sincosf(th,&s,&c); cN[j]=c; sN[j]=s;
            phz[j] = 0.5f*pg[rzoff + q];
        }
    }
    __syncthreads();
    const unsigned t = tid;
    float2* sp = st + ((size_t)b<<16);
    float2 a[32];
    // ---- T3 load: f = (i&3) | (t<<2) | ((i>>2)<<10) | (outer<<13)
    #pragma unroll
    for (int u=0;u<8;u++){
        unsigned fb = (t<<2) | ((unsigned)u<<10) | (outer<<13);
        const float4* s4 = (const float4*)(sp + fb);
        float4 v0=s4[0], v1=s4[1];
        a[4*u+0]=make_float2(v0.x,v0.y); a[4*u+1]=make_float2(v0.z,v0.w);
        a[4*u+2]=make_float2(v1.x,v1.y); a[4*u+3]=make_float2(v1.z,v1.w);
    }
    if (MODE>=1){
        // Ry_l(f10,f11,f12): targets i bits 2,3,4
        #pragma unroll
        for (int j=0;j<32;j++){ if (j&4)  continue; ry_pair(a[j],a[j|4] ,cP[10],sP[10]); }
        #pragma unroll
        for (int j=0;j<32;j++){ if (j&8)  continue; ry_pair(a[j],a[j|8] ,cP[11],sP[11]); }
        #pragma unroll
        for (int j=0;j<32;j++){ if (j&16) continue; ry_pair(a[j],a[j|16],cP[12],sP[12]); }
    }
    // CN_l(13->12): control f13 = outer bit0 (uniform), target i bit4
    if (outer & 1u){
        #pragma unroll
        for (int j=0;j<32;j++){ if (j&16) continue; float2 tm=a[j]; a[j]=a[j|16]; a[j|16]=tm; }
    }
    // CN_l(12->11): control i bit4, target i bit3
    #pragma unroll
    for (int j=0;j<32;j++){ if (j&8) continue; if ((j>>4)&1){ float2 tm=a[j]; a[j]=a[j|8]; a[j|8]=tm; } }
    // CN_l(11->10): control i bit3, target i bit2
    #pragma unroll
    for (int j=0;j<32;j++){ if (j&4) continue; if ((j>>3)&1){ float2 tm=a[j]; a[j]=a[j|4]; a[j|4]=tm; } }
    // ---- transpose T3 -> T2
    #pragma unroll
    for (int i=0;i<32;i++) tile[swz((unsigned)(i&3) | (t<<2) | ((unsigned)(i>>2)<<10))] = a[i];
    __syncthreads();
    #pragma unroll
    for (int i=0;i<32;i++) a[i] = tile[swz((t&31u) | ((unsigned)i<<5) | ((t>>5)<<10))];
    // T2: f5..9 = i bits 0..4; f10..12 = t>>5; f0..4 = t&31
    // CN_l(10->9): control f10 = (t>>5)&1 (fixed), target i bit4
    if ((t>>5)&1u){
        #pragma unroll
        for (int j=0;j<32;j++){ if (j&16) continue; float2 tm=a[j]; a[j]=a[j|16]; a[j|16]=tm; }
    }
    // CN_l(9->8),(8->7),(7->6),(6->5): control i bit qq+1, target i bit qq
    #pragma unroll
    for (int qq=3;qq>=0;qq--){
        const int bit = 1<<qq;
        #pragma unroll
        for (int j=0;j<32;j++){ if (j&bit) continue; if ((j>>(qq+1))&1){ float2 tm=a[j]; a[j]=a[j|bit]; a[j|bit]=tm; } }
    }
    // ---- transpose T2 -> T1 (same-slot write-back, sync, re-read)
    #pragma unroll
    for (int i=0;i<32;i++) tile[swz((t&31u) | ((unsigned)i<<5) | ((t>>5)<<10))] = a[i];
    __syncthreads();
    #pragma unroll
    for (int i=0;i<32;i++) a[i] = tile[swz((unsigned)i | (t<<5))];
    // T1: f0..4 = i; f5..12 = t; f13..15 = outer
    // CN_l(5->4): control f5 = t bit0, target i bit4
    if (t & 1u){
        #pragma unroll
        for (int j=0;j<32;j++){ if (j&16) continue; float2 tm=a[j]; a[j]=a[j|16]; a[j|16]=tm; }
    }
    // CN_l(4->3),(3->2),(2->1),(1->0)
    #pragma unroll
    for (int qq=3;qq>=0;qq--){
        const int bit = 1<<qq;
        #pragma unroll
        for (int j=0;j<32;j++){ if (j&bit) continue; if ((j>>(qq+1))&1){ float2 tm=a[j]; a[j]=a[j|bit]; a[j|bit]=tm; } }
    }
    if (MODE<=1){
        // Rz_l on flat bits 0..14 (bit 15 deferred to the B-pass)
        float ab = 0.0f;
        #pragma unroll
        for (int j=5;j<13;j++) ab += ((t>>(j-5))&1u)? phz[j] : -phz[j];
        ab += (outer&1u)?      phz[13] : -phz[13];
        ab += ((outer>>1)&1u)? phz[14] : -phz[14];
        #pragma unroll
        for (int i=0;i<32;i++){
            float al = ab;
            al += (i&1)?      phz[0] : -phz[0];
            al += ((i>>1)&1)? phz[1] : -phz[1];
            al += ((i>>2)&1)? phz[2] : -phz[2];
            al += ((i>>3)&1)? phz[3] : -phz[3];
            al += ((i>>4)&1)? phz[4] : -phz[4];
            float sn,cs; __sincosf(al,&sn,&cs);
            float2 v=a[i];
            a[i]=make_float2(v.x*cs - v.y*sn, v.x*sn + v.y*cs);
        }
        // Ry_{l+1}(f1..f4): targets i bits 1..4
        #pragma unroll
        for (int qq=1;qq<=4;qq++){
            const int bit = 1<<qq;
            const float c=cN[qq], s=sN[qq];
            #pragma unroll
            for (int j=0;j<32;j++){ if (j&bit) continue; ry_pair(a[j],a[j|bit],c,s); }
        }
        // store T1: 32 consecutive amps per thread
        float2* dst = sp + ((t<<5) | (outer<<13));
        #pragma unroll
        for (int u=0;u<8;u++){
            float4* d4 = (float4*)(dst + 4*u);
            d4[0]=make_float4(a[4*u+0].x,a[4*u+0].y,a[4*u+1].x,a[4*u+1].y);
            d4[1]=make_float4(a[4*u+2].x,a[4*u+2].y,a[4*u+3].x,a[4*u+3].y);
        }
    } else {
        // measurement: q0: (-1)^{f15^f0}; q1: (-1)^{f14}; q2: (-1)^{f13}
        float s0=0.f, s1=0.f;
        #pragma unroll
        for (int i=0;i<32;i++){
            float pr = a[i].x*a[i].x + a[i].y*a[i].y;
            s1 += pr;
            s0 += (i&1)? -pr : pr;
        }
        float v0 = ((outer>>2)&1u)? -s0 : s0;
        float v1 = ((outer>>1)&1u)? -s1 : s1;
        float v2 = (outer&1u)?      -s1 : s1;
        #pragma unroll
        for (int off=32; off>0; off>>=1){
            v0 += __shfl_down(v0, off);
            v1 += __shfl_down(v1, off);
            v2 += __shfl_down(v2, off);
        }
        const int wv = tid>>6, ln = tid&63;
        if (ln==0){ red[wv][0]=v0; red[wv][1]=v1; red[wv][2]=v2; }
        __syncthreads();
        if (tid<3){
            float s = red[0][tid]+red[1][tid]+red[2][tid]+red[3][tid];
            atomicAdd(&outg[b*3+tid], s);
        }
    }
}

// ---------------- Type-B pass (outer = f bits 10..12; local f bits {0..9,13,14,15})
// CN_l(0->15), Rz_l(f15), Ry_{l+1}(f0,f13,f14,f15), CN_{l+1}(15->14),(14->13), Ry_{l+1}(f5..f9)
__global__ __launch_bounds__(256) void k_B(const float* __restrict__ xg,
                                           const float* __restrict__ pg,
                                           float2* __restrict__ st,
                                           int rzoff, int nxoff)
{
    __shared__ float2 tile[8192];
    __shared__ float cN[16], sN[16];
    __shared__ float snp, csp;   // sincos(+phi) for Rz_l(qubit0 = flat bit 15)
    const int tid = threadIdx.x;
    const int b = blockIdx.x >> 3;
    const unsigned outer = blockIdx.x & 7u;        // f bits 10..12
    if (tid < 16){
        int j=tid, q=15-j;
        float th = 0.5f*(xg[b*16+q]*PI_F + pg[nxoff + q]);
        float s,c; __sincosf(th,&s,&c);
        cN[j]=c; sN[j]=s;
    }
    if (tid==16){ float phi = 0.5f*pg[rzoff + 0]; float s,c; __sincosf(phi,&s,&c); snp=s; csp=c; }
    __syncthreads();
    const unsigned t = tid;
    float2* sp = st + ((size_t)b<<16);
    float2 a[32];
    // T3 load: f = (i&3) | (t<<2) | (outer<<10) | ((i>>2)<<13)
    #pragma unroll
    for (int u=0;u<8;u++){
        unsigned fb = (t<<2) | (outer<<10) | ((unsigned)u<<13);
        const float4* s4 = (const float4*)(sp + fb);
        float4 v0=s4[0], v1=s4[1];
        a[4*u+0]=make_float2(v0.x,v0.y); a[4*u+1]=make_float2(v0.z,v0.w);
        a[4*u+2]=make_float2(v1.x,v1.y); a[4*u+3]=make_float2(v1.z,v1.w);
    }
    // CN_l(0->15): control f0 = i bit0, target f15 = i bit4
    #pragma unroll
    for (int j=0;j<32;j++){ if (j&16) continue; if (j&1){ float2 tm=a[j]; a[j]=a[j|16]; a[j|16]=tm; } }
    // Rz_l(f15): bit = i bit4 ; angle = bit? +phi : -phi
    #pragma unroll
    for (int j=0;j<32;j++){
        float sn = ((j>>4)&1)? snp : -snp;
        float2 v=a[j];
        a[j]=make_float2(v.x*csp - v.y*sn, v.x*sn + v.y*csp);
    }
    // Ry_{l+1}(f0): target i bit0
    #pragma unroll
    for (int j=0;j<32;j++){ if (j&1)  continue; ry_pair(a[j],a[j|1] ,cN[0] ,sN[0]);  }
    // Ry_{l+1}(f13,f14,f15): targets i bits 2,3,4
    #pragma unroll
    for (int j=0;j<32;j++){ if (j&4)  continue; ry_pair(a[j],a[j|4] ,cN[13],sN[13]); }
    #pragma unroll
    for (int j=0;j<32;j++){ if (j&8)  continue; ry_pair(a[j],a[j|8] ,cN[14],sN[14]); }
    #pragma unroll
    for (int j=0;j<32;j++){ if (j&16) continue; ry_pair(a[j],a[j|16],cN[15],sN[15]); }
    // CN_{l+1}(15->14): control i bit4, target i bit3
    #pragma unroll
    for (int j=0;j<32;j++){ if (j&8) continue; if ((j>>4)&1){ float2 tm=a[j]; a[j]=a[j|8]; a[j|8]=tm; } }
    // CN_{l+1}(14->13): control i bit3, target i bit2
    #pragma unroll
    for (int j=0;j<32;j++){ if (j&4) continue; if ((j>>3)&1){ float2 tm=a[j]; a[j]=a[j|4]; a[j|4]=tm; } }
    // transpose T3 -> T2
    #pragma unroll
    for (int i=0;i<32;i++) tile[swz((unsigned)(i&3) | (t<<2) | ((unsigned)(i>>2)<<10))] = a[i];
    __syncthreads();
    #pragma unroll
    for (int i=0;i<32;i++) a[i] = tile[swz((t&31u) | ((unsigned)i<<5) | ((t>>5)<<10))];
    // T2: f5..9 = i bits 0..4 ; f0..4 = t&31 ; f13..15 = t>>5
    // Ry_{l+1}(f5..f9)
    #pragma unroll
    for (int qq=0;qq<5;qq++){
        const int bit = 1<<qq;
        const float c=cN[5+qq], s=sN[5+qq];
        #pragma unroll
        for (int j=0;j<32;j++){ if (j&bit) continue; ry_pair(a[j],a[j|bit],c,s); }
    }
    // store T2: f = (t&31) | (i<<5) | (outer<<10) | ((t>>5)<<13)
    #pragma unroll
    for (int i=0;i<32;i++){
        unsigned f = (t&31u) | ((unsigned)i<<5) | (outer<<10) | ((t>>5)<<13);
        sp[f] = a[i];
    }
}

extern "C" void kernel_launch(void* const* d_in, const int* in_sizes, int n_in,
                              void* d_out, int out_size, void* d_ws, size_t ws_size,
                              hipStream_t stream)
{
    const float* x = (const float*)d_in[0];
    const float* params = (const float*)d_in[1];
    float* out = (float*)d_out;
    float2* st = (float2*)d_ws;
    const int B = in_sizes[0] / 16;

    hipMemsetAsync(d_out, 0, (size_t)out_size*sizeof(float), stream);

    const size_t per = (size_t)65536 * sizeof(float2);   // 512 KB per batch element
    int chunk = (int)(ws_size / per);
    if (chunk < 1) chunk = 1;
    if (chunk > B) chunk = B;
    for (int b0=0; b0<B; b0+=chunk){
        const int nb = (B-b0 < chunk) ? (B-b0) : chunk;
        dim3 gr(nb*8), bl(256);
        const float* xb = x + (size_t)b0*16;
        float* ob = out + (size_t)b0*3;
        hipLaunchKernelGGL(k_gen,      gr, bl, 0, stream, xb, params, st);
        hipLaunchKernelGGL(k_A<0>,     gr, bl, 0, stream, xb, params, st, ob);
        hipLaunchKernelGGL(k_B,        gr, bl, 0, stream, xb, params, st, 16, 32);
        hipLaunchKernelGGL(k_A<1>,     gr, bl, 0, stream, xb, params, st, ob);
        hipLaunchKernelGGL(k_B,        gr, bl, 0, stream, xb, params, st, 48, 64);
        hipLaunchKernelGGL(k_A<2>,     gr, bl, 0, stream, xb, params, st, ob);
    }
}

// Round 3
// 421.214 us; speedup vs baseline: 1.3322x; 1.3322x over previous
//
#include <hip/hip_runtime.h>
#include <hip/hip_bf16.h>

#define PI_F 3.14159265f

// Flat index convention: state.reshape((2,)*16) => qubit q corresponds to
// flat bit j = 15 - q.  Circuit per layer (flat-bit gates):
//   Ry on all flat bits j (angle of qubit 15-j)
//   CNOT chain: (c=15,t=14),(14,13),...,(1,0),(0,15)
//   Rz on all flat bits
// Measurement: <Z_q> q=0,1,2  ->  flat bits 15,14,13.
//
// Pass structure (4 passes over the 512KB/element state in d_ws):
//   P1 k_gen2 (B-type, outer=f10..12, WRITE): chain1 folded into generation
//      (CNOT chain = GF(2)-linear index map; pre-chain bit b_pre[j]=b[j]^b[j+1]
//      j=0..13, b_pre[14]=b14^b0^b15, b_pre[15]=b0^b15), Rz1 pointwise,
//      Ry2 targets {0..9,13,14,15}, CN2(15->14),(14->13).
//   P2 k_A<1> (A-type, outer=f13..15, RW): Ry2(10..12), chain2 targets 12..0,
//      Rz2(0..14), Ry3(1..4).                       [verified in round 2]
//   P3 k_B (B-type, RW): CN2(0->15), Rz2(f15), Ry3(0,13,14,15),
//      CN3(15->14),(14->13), Ry3(5..9).             [verified in round 2]
//   P4 k_A<2> (A-type, READ): Ry3(10..12), chain3 targets 12..0, measurement
//      with CN3(0->15) folded into sign (Z_f15 -> Z_f15 Z_f0), Rz3 dropped.
// Chunked at 256 elements (128MB) so intermediate passes are L3-resident.

__device__ __forceinline__ unsigned swz(unsigned l){ return l ^ ((l>>5)&31u); }

__device__ __forceinline__ void ry_pair(float2& A0, float2& A1, float c, float s){
    float2 a0=A0, a1=A1;
    A0 = make_float2(c*a0.x - s*a1.x, c*a0.y - s*a1.y);
    A1 = make_float2(s*a0.x + c*a1.x, s*a0.y + c*a1.y);
}

// ---------------- P1: generate post-chain1 state + Rz1 + Ry2{0..9,13..15} + CN2 front
__global__ __launch_bounds__(256) void k_gen2(const float* __restrict__ xg,
                                              const float* __restrict__ pg,
                                              float2* __restrict__ st)
{
    __shared__ float2 tile[8192];
    __shared__ float cA[16], sA[16], cN[16], sN[16], phz[16];
    const int tid = threadIdx.x;
    const int b = blockIdx.x >> 3;
    const unsigned o = blockIdx.x & 7u;            // f bits 10..12
    if (tid < 16){
        int j = tid, q = 15 - j;
        float th = 0.5f*(xg[b*16+q]*PI_F + pg[q]);           // Ry1
        __sincosf(th, &sA[j], &cA[j]);
    } else if (tid < 32){
        int j = tid-16, q = 15 - j;
        float th = 0.5f*(xg[b*16+q]*PI_F + pg[32+q]);        // Ry2
        __sincosf(th, &sN[j], &cN[j]);
    } else if (tid < 48){
        int j = tid-32, q = 15 - j;
        phz[j] = 0.5f*pg[16+q];                               // Rz1
    }
    __syncthreads();
    const unsigned t = tid;
    // T1 layout: f0..4 = i ; f5..9 = t&31 ; f10..12 = o ; f13..15 = t>>5
    const unsigned f5_9 = t & 31u, f13_15 = t >> 5;
    float base = 1.0f;
    {
        // hb bits 0..10 = f5..f15
        const unsigned hb = f5_9 | (o<<5) | (f13_15<<8);
        #pragma unroll
        for (int j=5;j<=13;j++){
            int v = (int)(((hb>>(j-5)) ^ (hb>>(j-4))) & 1u);  // b_pre[j]=f_j^f_{j+1}
            base *= v ? sA[j] : cA[j];
        }
    }
    float phb = 0.0f;
    {
        #pragma unroll
        for (int j=5;j<10;j++)  phb += ((f5_9>>(j-5))&1u)   ? phz[j] : -phz[j];
        #pragma unroll
        for (int j=10;j<13;j++) phb += ((o>>(j-10))&1u)     ? phz[j] : -phz[j];
        #pragma unroll
        for (int j=13;j<16;j++) phb += ((f13_15>>(j-13))&1u)? phz[j] : -phz[j];
    }
    const int f5b  = (int)(t & 1u);
    const int f14b = (int)((t>>6)&1u);
    const int f15b = (int)((t>>7)&1u);
    float2 a[32];
    #pragma unroll
    for (int i=0;i<32;i++){
        const int i0=i&1, i1=(i>>1)&1, i2=(i>>2)&1, i3=(i>>3)&1, i4=(i>>4)&1;
        float pr = base;
        pr *= (i0^i1)? sA[0]:cA[0];
        pr *= (i1^i2)? sA[1]:cA[1];
        pr *= (i2^i3)? sA[2]:cA[2];
        pr *= (i3^i4)? sA[3]:cA[3];
        pr *= (i4^f5b)? sA[4]:cA[4];
        pr *= (f14b^i0^f15b)? sA[14]:cA[14];
        pr *= (i0^f15b)? sA[15]:cA[15];
        float ph = phb;
        ph += i0? phz[0]:-phz[0];
        ph += i1? phz[1]:-phz[1];
        ph += i2? phz[2]:-phz[2];
        ph += i3? phz[3]:-phz[3];
        ph += i4? phz[4]:-phz[4];
        float sn,cs; __sincosf(ph,&sn,&cs);
        a[i] = make_float2(pr*cs, pr*sn);
    }
    // Ry2 targets f0..f4 (i bits 0..4)
    #pragma unroll
    for (int qq=0;qq<5;qq++){
        const int bit=1<<qq;
        const float c=cN[qq], s=sN[qq];
        #pragma unroll
        for (int j=0;j<32;j++){ if (j&bit) continue; ry_pair(a[j],a[j|bit],c,s); }
    }
    // T1 -> T2
    #pragma unroll
    for (int i=0;i<32;i++) tile[swz((unsigned)i | (f5_9<<5) | (f13_15<<10))] = a[i];
    __syncthreads();
    #pragma unroll
    for (int i=0;i<32;i++) a[i] = tile[swz((t&31u) | ((unsigned)i<<5) | ((t>>5)<<10))];
    // T2: f0..4 = t&31 ; f5..9 = i ; f13..15 = t>>5
    #pragma unroll
    for (int qq=0;qq<5;qq++){
        const int bit=1<<qq;
        const float c=cN[5+qq], s=sN[5+qq];
        #pragma unroll
        for (int j=0;j<32;j++){ if (j&bit) continue; ry_pair(a[j],a[j|bit],c,s); }
    }
    // T2 -> T3
    #pragma unroll
    for (int i=0;i<32;i++) tile[swz((t&31u) | ((unsigned)i<<5) | ((t>>5)<<10))] = a[i];
    __syncthreads();
    #pragma unroll
    for (int i=0;i<32;i++) a[i] = tile[swz((unsigned)(i&3) | (t<<2) | ((unsigned)(i>>2)<<10))];
    // T3: f0,f1 = i&3 ; f2..9 = t ; f13..15 = i>>2
    // Ry2 targets f13,f14,f15 = i bits 2,3,4
    #pragma unroll
    for (int j=0;j<32;j++){ if (j&4)  continue; ry_pair(a[j],a[j|4] ,cN[13],sN[13]); }
    #pragma unroll
    for (int j=0;j<32;j++){ if (j&8)  continue; ry_pair(a[j],a[j|8] ,cN[14],sN[14]); }
    #pragma unroll
    for (int j=0;j<32;j++){ if (j&16) continue; ry_pair(a[j],a[j|16],cN[15],sN[15]); }
    // CN2(15->14): ctrl i bit4, tgt i bit3 ; CN2(14->13): ctrl i bit3, tgt i bit2
    #pragma unroll
    for (int j=0;j<32;j++){ if (j&8) continue; if ((j>>4)&1){ float2 tm=a[j]; a[j]=a[j|8]; a[j|8]=tm; } }
    #pragma unroll
    for (int j=0;j<32;j++){ if (j&4) continue; if ((j>>3)&1){ float2 tm=a[j]; a[j]=a[j|4]; a[j|4]=tm; } }
    float2* sp = st + ((size_t)b<<16);
    #pragma unroll
    for (int u=0;u<8;u++){
        unsigned fb = (t<<2) | (o<<10) | ((unsigned)u<<13);
        float4* d4 = (float4*)(sp + fb);
        d4[0]=make_float4(a[4*u+0].x,a[4*u+0].y,a[4*u+1].x,a[4*u+1].y);
        d4[1]=make_float4(a[4*u+2].x,a[4*u+2].y,a[4*u+3].x,a[4*u+3].y);
    }
}

// ---------------- Type-A pass (outer = f bits 13..15; local f bits 0..12)
// MODE 1: Ry2(10..12) + layer2 chain mid + Rz2(0..14) + Ry3(1..4)
// MODE 2: Ry3(10..12) + layer3 chain mid + measurement
template<int MODE>
__global__ __launch_bounds__(256) void k_A(const float* __restrict__ xg,
                                           const float* __restrict__ pg,
                                           float2* __restrict__ st,
                                           float* __restrict__ outg)
{
    __shared__ float2 tile[8192];
    __shared__ float cP[16], sP[16], cN[16], sN[16], phz[16];
    __shared__ float red[4][3];
    const int tid = threadIdx.x;
    const int b = blockIdx.x >> 3;
    const unsigned outer = blockIdx.x & 7u;        // f bits 13..15
    const int prevoff = (MODE==1)? 32 : 64;        // Ry layer l
    const int rzoff   = 48;                        // Rz layer l   (MODE1 only)
    const int nxoff   = 64;                        // Ry layer l+1 (MODE1 only)
    if (tid < 16){
        int j=tid, q=15-j;
        { float th=0.5f*(xg[b*16+q]*PI_F + pg[prevoff+q]); float s,c; __sincosf(th,&s,&c); cP[j]=c; sP[j]=s; }
        if (MODE==1){
            float th=0.5f*(xg[b*16+q]*PI_F + pg[nxoff+q]); float s,c; __sincosf(th,&s,&c); cN[j]=c; sN[j]=s;
            phz[j] = 0.5f*pg[rzoff + q];
        }
    }
    __syncthreads();
    const unsigned t = tid;
    float2* sp = st + ((size_t)b<<16);
    float2 a[32];
    // ---- T3 load: f = (i&3) | (t<<2) | ((i>>2)<<10) | (outer<<13)
    #pragma unroll
    for (int u=0;u<8;u++){
        unsigned fb = (t<<2) | ((unsigned)u<<10) | (outer<<13);
        const float4* s4 = (const float4*)(sp + fb);
        float4 v0=s4[0], v1=s4[1];
        a[4*u+0]=make_float2(v0.x,v0.y); a[4*u+1]=make_float2(v0.z,v0.w);
        a[4*u+2]=make_float2(v1.x,v1.y); a[4*u+3]=make_float2(v1.z,v1.w);
    }
    // Ry_l(f10,f11,f12): targets i bits 2,3,4
    #pragma unroll
    for (int j=0;j<32;j++){ if (j&4)  continue; ry_pair(a[j],a[j|4] ,cP[10],sP[10]); }
    #pragma unroll
    for (int j=0;j<32;j++){ if (j&8)  continue; ry_pair(a[j],a[j|8] ,cP[11],sP[11]); }
    #pragma unroll
    for (int j=0;j<32;j++){ if (j&16) continue; ry_pair(a[j],a[j|16],cP[12],sP[12]); }
    // CN_l(13->12): control f13 = outer bit0 (uniform), target i bit4
    if (outer & 1u){
        #pragma unroll
        for (int j=0;j<32;j++){ if (j&16) continue; float2 tm=a[j]; a[j]=a[j|16]; a[j|16]=tm; }
    }
    // CN_l(12->11): control i bit4, target i bit3
    #pragma unroll
    for (int j=0;j<32;j++){ if (j&8) continue; if ((j>>4)&1){ float2 tm=a[j]; a[j]=a[j|8]; a[j|8]=tm; } }
    // CN_l(11->10): control i bit3, target i bit2
    #pragma unroll
    for (int j=0;j<32;j++){ if (j&4) continue; if ((j>>3)&1){ float2 tm=a[j]; a[j]=a[j|4]; a[j|4]=tm; } }
    // ---- transpose T3 -> T2
    #pragma unroll
    for (int i=0;i<32;i++) tile[swz((unsigned)(i&3) | (t<<2) | ((unsigned)(i>>2)<<10))] = a[i];
    __syncthreads();
    #pragma unroll
    for (int i=0;i<32;i++) a[i] = tile[swz((t&31u) | ((unsigned)i<<5) | ((t>>5)<<10))];
    // T2: f5..9 = i bits 0..4; f10..12 = t>>5; f0..4 = t&31
    // CN_l(10->9): control f10 = (t>>5)&1 (fixed), target i bit4
    if ((t>>5)&1u){
        #pragma unroll
        for (int j=0;j<32;j++){ if (j&16) continue; float2 tm=a[j]; a[j]=a[j|16]; a[j|16]=tm; }
    }
    // CN_l(9->8),(8->7),(7->6),(6->5)
    #pragma unroll
    for (int qq=3;qq>=0;qq--){
        const int bit = 1<<qq;
        #pragma unroll
        for (int j=0;j<32;j++){ if (j&bit) continue; if ((j>>(qq+1))&1){ float2 tm=a[j]; a[j]=a[j|bit]; a[j|bit]=tm; } }
    }
    // ---- transpose T2 -> T1
    #pragma unroll
    for (int i=0;i<32;i++) tile[swz((t&31u) | ((unsigned)i<<5) | ((t>>5)<<10))] = a[i];
    __syncthreads();
    #pragma unroll
    for (int i=0;i<32;i++) a[i] = tile[swz((unsigned)i | (t<<5))];
    // T1: f0..4 = i; f5..12 = t; f13..15 = outer
    // CN_l(5->4): control f5 = t bit0, target i bit4
    if (t & 1u){
        #pragma unroll
        for (int j=0;j<32;j++){ if (j&16) continue; float2 tm=a[j]; a[j]=a[j|16]; a[j|16]=tm; }
    }
    // CN_l(4->3),(3->2),(2->1),(1->0)
    #pragma unroll
    for (int qq=3;qq>=0;qq--){
        const int bit = 1<<qq;
        #pragma unroll
        for (int j=0;j<32;j++){ if (j&bit) continue; if ((j>>(qq+1))&1){ float2 tm=a[j]; a[j]=a[j|bit]; a[j|bit]=tm; } }
    }
    if (MODE==1){
        // Rz_l on flat bits 0..14 (bit 15 deferred to the B-pass)
        float ab = 0.0f;
        #pragma unroll
        for (int j=5;j<13;j++) ab += ((t>>(j-5))&1u)? phz[j] : -phz[j];
        ab += (outer&1u)?      phz[13] : -phz[13];
        ab += ((outer>>1)&1u)? phz[14] : -phz[14];
        #pragma unroll
        for (int i=0;i<32;i++){
            float al = ab;
            al += (i&1)?      phz[0] : -phz[0];
            al += ((i>>1)&1)? phz[1] : -phz[1];
            al += ((i>>2)&1)? phz[2] : -phz[2];
            al += ((i>>3)&1)? phz[3] : -phz[3];
            al += ((i>>4)&1)? phz[4] : -phz[4];
            float sn,cs; __sincosf(al,&sn,&cs);
            float2 v=a[i];
            a[i]=make_float2(v.x*cs - v.y*sn, v.x*sn + v.y*cs);
        }
        // Ry_{l+1}(f1..f4): targets i bits 1..4
        #pragma unroll
        for (int qq=1;qq<=4;qq++){
            const int bit = 1<<qq;
            const float c=cN[qq], s=sN[qq];
            #pragma unroll
            for (int j=0;j<32;j++){ if (j&bit) continue; ry_pair(a[j],a[j|bit],c,s); }
        }
        float2* dst = sp + ((t<<5) | (outer<<13));
        #pragma unroll
        for (int u=0;u<8;u++){
            float4* d4 = (float4*)(dst + 4*u);
            d4[0]=make_float4(a[4*u+0].x,a[4*u+0].y,a[4*u+1].x,a[4*u+1].y);
            d4[1]=make_float4(a[4*u+2].x,a[4*u+2].y,a[4*u+3].x,a[4*u+3].y);
        }
    } else {
        // measurement: q0: (-1)^{f15^f0}; q1: (-1)^{f14}; q2: (-1)^{f13}
        float s0=0.f, s1=0.f;
        #pragma unroll
        for (int i=0;i<32;i++){
            float pr = a[i].x*a[i].x + a[i].y*a[i].y;
            s1 += pr;
            s0 += (i&1)? -pr : pr;
        }
        float v0 = ((outer>>2)&1u)? -s0 : s0;
        float v1 = ((outer>>1)&1u)? -s1 : s1;
        float v2 = (outer&1u)?      -s1 : s1;
        #pragma unroll
        for (int off=32; off>0; off>>=1){
            v0 += __shfl_down(v0, off);
            v1 += __shfl_down(v1, off);
            v2 += __shfl_down(v2, off);
        }
        const int wv = tid>>6, ln = tid&63;
        if (ln==0){ red[wv][0]=v0; red[wv][1]=v1; red[wv][2]=v2; }
        __syncthreads();
        if (tid<3){
            float s = red[0][tid]+red[1][tid]+red[2][tid]+red[3][tid];
            atomicAdd(&outg[b*3+tid], s);
        }
    }
}

// ---------------- Type-B pass (outer = f bits 10..12)
// CN_l(0->15), Rz_l(f15), Ry_{l+1}(f0,f13,f14,f15), CN_{l+1}(15->14),(14->13), Ry_{l+1}(f5..f9)
__global__ __launch_bounds__(256) void k_B(const float* __restrict__ xg,
                                           const float* __restrict__ pg,
                                           float2* __restrict__ st,
                                           int rzoff, int nxoff)
{
    __shared__ float2 tile[8192];
    __shared__ float cN[16], sN[16];
    __shared__ float snp, csp;
    const int tid = threadIdx.x;
    const int b = blockIdx.x >> 3;
    const unsigned outer = blockIdx.x & 7u;        // f bits 10..12
    if (tid < 16){
        int j=tid, q=15-j;
        float th = 0.5f*(xg[b*16+q]*PI_F + pg[nxoff + q]);
        float s,c; __sincosf(th,&s,&c);
        cN[j]=c; sN[j]=s;
    }
    if (tid==16){ float phi = 0.5f*pg[rzoff + 0]; float s,c; __sincosf(phi,&s,&c); snp=s; csp=c; }
    __syncthreads();
    const unsigned t = tid;
    float2* sp = st + ((size_t)b<<16);
    float2 a[32];
    #pragma unroll
    for (int u=0;u<8;u++){
        unsigned fb = (t<<2) | (outer<<10) | ((unsigned)u<<13);
        const float4* s4 = (const float4*)(sp + fb);
        float4 v0=s4[0], v1=s4[1];
        a[4*u+0]=make_float2(v0.x,v0.y); a[4*u+1]=make_float2(v0.z,v0.w);
        a[4*u+2]=make_float2(v1.x,v1.y); a[4*u+3]=make_float2(v1.z,v1.w);
    }
    // CN_l(0->15): control f0 = i bit0, target f15 = i bit4
    #pragma unroll
    for (int j=0;j<32;j++){ if (j&16) continue; if (j&1){ float2 tm=a[j]; a[j]=a[j|16]; a[j|16]=tm; } }
    // Rz_l(f15)
    #pragma unroll
    for (int j=0;j<32;j++){
        float sn = ((j>>4)&1)? snp : -snp;
        float2 v=a[j];
        a[j]=make_float2(v.x*csp - v.y*sn, v.x*sn + v.y*csp);
    }
    // Ry_{l+1}(f0): target i bit0
    #pragma unroll
    for (int j=0;j<32;j++){ if (j&1)  continue; ry_pair(a[j],a[j|1] ,cN[0] ,sN[0]);  }
    // Ry_{l+1}(f13,f14,f15): targets i bits 2,3,4
    #pragma unroll
    for (int j=0;j<32;j++){ if (j&4)  continue; ry_pair(a[j],a[j|4] ,cN[13],sN[13]); }
    #pragma unroll
    for (int j=0;j<32;j++){ if (j&8)  continue; ry_pair(a[j],a[j|8] ,cN[14],sN[14]); }
    #pragma unroll
    for (int j=0;j<32;j++){ if (j&16) continue; ry_pair(a[j],a[j|16],cN[15],sN[15]); }
    // CN_{l+1}(15->14),(14->13)
    #pragma unroll
    for (int j=0;j<32;j++){ if (j&8) continue; if ((j>>4)&1){ float2 tm=a[j]; a[j]=a[j|8]; a[j|8]=tm; } }
    #pragma unroll
    for (int j=0;j<32;j++){ if (j&4) continue; if ((j>>3)&1){ float2 tm=a[j]; a[j]=a[j|4]; a[j|4]=tm; } }
    // transpose T3 -> T2
    #pragma unroll
    for (int i=0;i<32;i++) tile[swz((unsigned)(i&3) | (t<<2) | ((unsigned)(i>>2)<<10))] = a[i];
    __syncthreads();
    #pragma unroll
    for (int i=0;i<32;i++) a[i] = tile[swz((t&31u) | ((unsigned)i<<5) | ((t>>5)<<10))];
    // T2: f5..9 = i ; f0..4 = t&31 ; f13..15 = t>>5
    #pragma unroll
    for (int qq=0;qq<5;qq++){
        const int bit = 1<<qq;
        const float c=cN[5+qq], s=sN[5+qq];
        #pragma unroll
        for (int j=0;j<32;j++){ if (j&bit) continue; ry_pair(a[j],a[j|bit],c,s); }
    }
    #pragma unroll
    for (int i=0;i<32;i++){
        unsigned f = (t&31u) | ((unsigned)i<<5) | (outer<<10) | ((t>>5)<<13);
        sp[f] = a[i];
    }
}

extern "C" void kernel_launch(void* const* d_in, const int* in_sizes, int n_in,
                              void* d_out, int out_size, void* d_ws, size_t ws_size,
                              hipStream_t stream)
{
    const float* x = (const float*)d_in[0];
    const float* params = (const float*)d_in[1];
    float* out = (float*)d_out;
    float2* st = (float2*)d_ws;
    const int B = in_sizes[0] / 16;

    hipMemsetAsync(d_out, 0, (size_t)out_size*sizeof(float), stream);

    const size_t per = (size_t)65536 * sizeof(float2);   // 512 KB per batch element
    int chunk = (int)(ws_size / per);
    if (chunk > 256) chunk = 256;                        // 128 MB working set -> L3-resident
    if (chunk < 1) chunk = 1;
    if (chunk > B) chunk = B;
    for (int b0=0; b0<B; b0+=chunk){
        const int nb = (B-b0 < chunk) ? (B-b0) : chunk;
        dim3 gr(nb*8), bl(256);
        const float* xb = x + (size_t)b0*16;
        float* ob = out + (size_t)b0*3;
        hipLaunchKernelGGL(k_gen2,  gr, bl, 0, stream, xb, params, st);
        hipLaunchKernelGGL(k_A<1>,  gr, bl, 0, stream, xb, params, st, ob);
        hipLaunchKernelGGL(k_B,     gr, bl, 0, stream, xb, params, st, 48, 64);
        hipLaunchKernelGGL(k_A<2>,  gr, bl, 0, stream, xb, params, st, ob);
    }
}

// Round 4
// 358.781 us; speedup vs baseline: 1.5641x; 1.1740x over previous
//
#include <hip/hip_runtime.h>
#include <hip/hip_bf16.h>

#define PI_F 3.14159265f

// Flat index convention: state.reshape((2,)*16) => qubit q corresponds to
// flat bit j = 15 - q.  Circuit per layer (flat-bit gates):
//   Ry on all flat bits j (angle of qubit 15-j)
//   CNOT chain: (c=15,t=14),(14,13),...,(1,0),(0,15)
//   Rz on all flat bits
// Measurement: <Z_q> q=0,1,2  ->  flat bits 15,14,13.
//
// Pass structure (4 passes over the 512KB/element state in d_ws):
//   P1 k_gen2 (B-type, outer=f10..12, WRITE): chain1 folded into generation,
//      Rz1 pointwise, Ry2 targets {0..9,13,14,15}, CN2(15->14),(14->13).
//   P2 k_A<1> (A-type, outer=f13..15, RW): Ry2(10..12), chain2 targets 12..0,
//      Rz2(0..14), Ry3(1..4).  Store via T1->T3 LDS transpose (coalesced).
//   P3 k_B (B-type, RW): CN2(0->15), Rz2(f15), Ry3(0,13,14,15),
//      CN3(15->14),(14->13), Ry3(5..9).
//   P4 k_A<2> (A-type, READ): Ry3(10..12), chain3 targets 12..0, measurement
//      with CN3(0->15) folded into sign (Z_f15 -> Z_f15 Z_f0), Rz3 dropped.
// Chunked at 256 elements (128MB) so intermediate passes are L3-resident.

__device__ __forceinline__ unsigned swz(unsigned l){ return l ^ ((l>>5)&31u); }

__device__ __forceinline__ void ry_pair(float2& A0, float2& A1, float c, float s){
    float2 a0=A0, a1=A1;
    A0 = make_float2(c*a0.x - s*a1.x, c*a0.y - s*a1.y);
    A1 = make_float2(s*a0.x + c*a1.x, s*a0.y + c*a1.y);
}

// ---------------- P1: generate post-chain1 state + Rz1 + Ry2{0..9,13..15} + CN2 front
__global__ __launch_bounds__(256) void k_gen2(const float* __restrict__ xg,
                                              const float* __restrict__ pg,
                                              float2* __restrict__ st)
{
    __shared__ float2 tile[8192];
    __shared__ float cA[16], sA[16], cN[16], sN[16], phz[16];
    const int tid = threadIdx.x;
    const int b = blockIdx.x >> 3;
    const unsigned o = blockIdx.x & 7u;            // f bits 10..12
    if (tid < 16){
        int j = tid, q = 15 - j;
        float th = 0.5f*(xg[b*16+q]*PI_F + pg[q]);           // Ry1
        __sincosf(th, &sA[j], &cA[j]);
    } else if (tid < 32){
        int j = tid-16, q = 15 - j;
        float th = 0.5f*(xg[b*16+q]*PI_F + pg[32+q]);        // Ry2
        __sincosf(th, &sN[j], &cN[j]);
    } else if (tid < 48){
        int j = tid-32, q = 15 - j;
        phz[j] = 0.5f*pg[16+q];                               // Rz1
    }
    __syncthreads();
    const unsigned t = tid;
    // T1 layout: f0..4 = i ; f5..9 = t&31 ; f10..12 = o ; f13..15 = t>>5
    const unsigned f5_9 = t & 31u, f13_15 = t >> 5;
    float base = 1.0f;
    {
        const unsigned hb = f5_9 | (o<<5) | (f13_15<<8);     // bits 0..10 = f5..f15
        #pragma unroll
        for (int j=5;j<=13;j++){
            int v = (int)(((hb>>(j-5)) ^ (hb>>(j-4))) & 1u); // b_pre[j]=f_j^f_{j+1}
            base *= v ? sA[j] : cA[j];
        }
    }
    float phb = 0.0f;
    {
        #pragma unroll
        for (int j=5;j<10;j++)  phb += ((f5_9>>(j-5))&1u)   ? phz[j] : -phz[j];
        #pragma unroll
        for (int j=10;j<13;j++) phb += ((o>>(j-10))&1u)     ? phz[j] : -phz[j];
        #pragma unroll
        for (int j=13;j<16;j++) phb += ((f13_15>>(j-13))&1u)? phz[j] : -phz[j];
    }
    const int f5b  = (int)(t & 1u);
    const int f14b = (int)((t>>6)&1u);
    const int f15b = (int)((t>>7)&1u);
    float2 a[32];
    #pragma unroll
    for (int i=0;i<32;i++){
        const int i0=i&1, i1=(i>>1)&1, i2=(i>>2)&1, i3=(i>>3)&1, i4=(i>>4)&1;
        float pr = base;
        pr *= (i0^i1)? sA[0]:cA[0];
        pr *= (i1^i2)? sA[1]:cA[1];
        pr *= (i2^i3)? sA[2]:cA[2];
        pr *= (i3^i4)? sA[3]:cA[3];
        pr *= (i4^f5b)? sA[4]:cA[4];
        pr *= (f14b^i0^f15b)? sA[14]:cA[14];
        pr *= (i0^f15b)? sA[15]:cA[15];
        float ph = phb;
        ph += i0? phz[0]:-phz[0];
        ph += i1? phz[1]:-phz[1];
        ph += i2? phz[2]:-phz[2];
        ph += i3? phz[3]:-phz[3];
        ph += i4? phz[4]:-phz[4];
        float sn,cs; __sincosf(ph,&sn,&cs);
        a[i] = make_float2(pr*cs, pr*sn);
    }
    // Ry2 targets f0..f4 (i bits 0..4)
    #pragma unroll
    for (int qq=0;qq<5;qq++){
        const int bit=1<<qq;
        const float c=cN[qq], s=sN[qq];
        #pragma unroll
        for (int j=0;j<32;j++){ if (j&bit) continue; ry_pair(a[j],a[j|bit],c,s); }
    }
    // T1 -> T2
    #pragma unroll
    for (int i=0;i<32;i++) tile[swz((unsigned)i | (f5_9<<5) | (f13_15<<10))] = a[i];
    __syncthreads();
    #pragma unroll
    for (int i=0;i<32;i++) a[i] = tile[swz((t&31u) | ((unsigned)i<<5) | ((t>>5)<<10))];
    // T2: f0..4 = t&31 ; f5..9 = i ; f13..15 = t>>5
    #pragma unroll
    for (int qq=0;qq<5;qq++){
        const int bit=1<<qq;
        const float c=cN[5+qq], s=sN[5+qq];
        #pragma unroll
        for (int j=0;j<32;j++){ if (j&bit) continue; ry_pair(a[j],a[j|bit],c,s); }
    }
    // T2 -> T3
    #pragma unroll
    for (int i=0;i<32;i++) tile[swz((t&31u) | ((unsigned)i<<5) | ((t>>5)<<10))] = a[i];
    __syncthreads();
    #pragma unroll
    for (int i=0;i<32;i++) a[i] = tile[swz((unsigned)(i&3) | (t<<2) | ((unsigned)(i>>2)<<10))];
    // T3: f0,f1 = i&3 ; f2..9 = t ; f13..15 = i>>2
    // Ry2 targets f13,f14,f15 = i bits 2,3,4
    #pragma unroll
    for (int j=0;j<32;j++){ if (j&4)  continue; ry_pair(a[j],a[j|4] ,cN[13],sN[13]); }
    #pragma unroll
    for (int j=0;j<32;j++){ if (j&8)  continue; ry_pair(a[j],a[j|8] ,cN[14],sN[14]); }
    #pragma unroll
    for (int j=0;j<32;j++){ if (j&16) continue; ry_pair(a[j],a[j|16],cN[15],sN[15]); }
    // CN2(15->14); CN2(14->13)
    #pragma unroll
    for (int j=0;j<32;j++){ if (j&8) continue; if ((j>>4)&1){ float2 tm=a[j]; a[j]=a[j|8]; a[j|8]=tm; } }
    #pragma unroll
    for (int j=0;j<32;j++){ if (j&4) continue; if ((j>>3)&1){ float2 tm=a[j]; a[j]=a[j|4]; a[j|4]=tm; } }
    float2* sp = st + ((size_t)b<<16);
    #pragma unroll
    for (int u=0;u<8;u++){
        unsigned fb = (t<<2) | (o<<10) | ((unsigned)u<<13);
        float4* d4 = (float4*)(sp + fb);
        d4[0]=make_float4(a[4*u+0].x,a[4*u+0].y,a[4*u+1].x,a[4*u+1].y);
        d4[1]=make_float4(a[4*u+2].x,a[4*u+2].y,a[4*u+3].x,a[4*u+3].y);
    }
}

// ---------------- Type-A pass (outer = f bits 13..15; local f bits 0..12)
// MODE 1: Ry2(10..12) + layer2 chain mid + Rz2(0..14) + Ry3(1..4)
// MODE 2: Ry3(10..12) + layer3 chain mid + measurement
template<int MODE>
__global__ __launch_bounds__(256) void k_A(const float* __restrict__ xg,
                                           const float* __restrict__ pg,
                                           float2* __restrict__ st,
                                           float* __restrict__ outg)
{
    __shared__ float2 tile[8192];
    __shared__ float cP[16], sP[16], cN[16], sN[16], phz[16];
    __shared__ float red[4][3];
    const int tid = threadIdx.x;
    const int b = blockIdx.x >> 3;
    const unsigned outer = blockIdx.x & 7u;        // f bits 13..15
    const int prevoff = (MODE==1)? 32 : 64;        // Ry layer l
    const int rzoff   = 48;                        // Rz layer l   (MODE1 only)
    const int nxoff   = 64;                        // Ry layer l+1 (MODE1 only)
    if (tid < 16){
        int j=tid, q=15-j;
        { float th=0.5f*(xg[b*16+q]*PI_F + pg[prevoff+q]); float s,c; __sincosf(th,&s,&c); cP[j]=c; sP[j]=s; }
        if (MODE==1){
            float th=0.5f*(xg[b*16+q]*PI_F + pg[nxoff+q]); float s,c; __sincosf(th,&s,&c); cN[j]=c; sN[j]=s;
            phz[j] = 0.5f*pg[rzoff + q];
        }
    }
    __syncthreads();
    const unsigned t = tid;
    float2* sp = st + ((size_t)b<<16);
    float2 a[32];
    // ---- T3 load: f = (i&3) | (t<<2) | ((i>>2)<<10) | (outer<<13)
    #pragma unroll
    for (int u=0;u<8;u++){
        unsigned fb = (t<<2) | ((unsigned)u<<10) | (outer<<13);
        const float4* s4 = (const float4*)(sp + fb);
        float4 v0=s4[0], v1=s4[1];
        a[4*u+0]=make_float2(v0.x,v0.y); a[4*u+1]=make_float2(v0.z,v0.w);
        a[4*u+2]=make_float2(v1.x,v1.y); a[4*u+3]=make_float2(v1.z,v1.w);
    }
    // Ry_l(f10,f11,f12): targets i bits 2,3,4
    #pragma unroll
    for (int j=0;j<32;j++){ if (j&4)  continue; ry_pair(a[j],a[j|4] ,cP[10],sP[10]); }
    #pragma unroll
    for (int j=0;j<32;j++){ if (j&8)  continue; ry_pair(a[j],a[j|8] ,cP[11],sP[11]); }
    #pragma unroll
    for (int j=0;j<32;j++){ if (j&16) continue; ry_pair(a[j],a[j|16],cP[12],sP[12]); }
    // CN_l(13->12): control f13 = outer bit0 (uniform), target i bit4
    if (outer & 1u){
        #pragma unroll
        for (int j=0;j<32;j++){ if (j&16) continue; float2 tm=a[j]; a[j]=a[j|16]; a[j|16]=tm; }
    }
    // CN_l(12->11): control i bit4, target i bit3
    #pragma unroll
    for (int j=0;j<32;j++){ if (j&8) continue; if ((j>>4)&1){ float2 tm=a[j]; a[j]=a[j|8]; a[j|8]=tm; } }
    // CN_l(11->10): control i bit3, target i bit2
    #pragma unroll
    for (int j=0;j<32;j++){ if (j&4) continue; if ((j>>3)&1){ float2 tm=a[j]; a[j]=a[j|4]; a[j|4]=tm; } }
    // ---- transpose T3 -> T2
    #pragma unroll
    for (int i=0;i<32;i++) tile[swz((unsigned)(i&3) | (t<<2) | ((unsigned)(i>>2)<<10))] = a[i];
    __syncthreads();
    #pragma unroll
    for (int i=0;i<32;i++) a[i] = tile[swz((t&31u) | ((unsigned)i<<5) | ((t>>5)<<10))];
    // T2: f5..9 = i bits 0..4; f10..12 = t>>5; f0..4 = t&31
    // CN_l(10->9): control f10 = (t>>5)&1 (fixed), target i bit4
    if ((t>>5)&1u){
        #pragma unroll
        for (int j=0;j<32;j++){ if (j&16) continue; float2 tm=a[j]; a[j]=a[j|16]; a[j|16]=tm; }
    }
    // CN_l(9->8),(8->7),(7->6),(6->5)
    #pragma unroll
    for (int qq=3;qq>=0;qq--){
        const int bit = 1<<qq;
        #pragma unroll
        for (int j=0;j<32;j++){ if (j&bit) continue; if ((j>>(qq+1))&1){ float2 tm=a[j]; a[j]=a[j|bit]; a[j|bit]=tm; } }
    }
    // ---- transpose T2 -> T1
    #pragma unroll
    for (int i=0;i<32;i++) tile[swz((t&31u) | ((unsigned)i<<5) | ((t>>5)<<10))] = a[i];
    __syncthreads();
    #pragma unroll
    for (int i=0;i<32;i++) a[i] = tile[swz((unsigned)i | (t<<5))];
    // T1: f0..4 = i; f5..12 = t; f13..15 = outer
    // CN_l(5->4): control f5 = t bit0, target i bit4
    if (t & 1u){
        #pragma unroll
        for (int j=0;j<32;j++){ if (j&16) continue; float2 tm=a[j]; a[j]=a[j|16]; a[j|16]=tm; }
    }
    // CN_l(4->3),(3->2),(2->1),(1->0)
    #pragma unroll
    for (int qq=3;qq>=0;qq--){
        const int bit = 1<<qq;
        #pragma unroll
        for (int j=0;j<32;j++){ if (j&bit) continue; if ((j>>(qq+1))&1){ float2 tm=a[j]; a[j]=a[j|bit]; a[j|bit]=tm; } }
    }
    if (MODE==1){
        // Rz_l on flat bits 0..14 (bit 15 deferred to the B-pass)
        float ab = 0.0f;
        #pragma unroll
        for (int j=5;j<13;j++) ab += ((t>>(j-5))&1u)? phz[j] : -phz[j];
        ab += (outer&1u)?      phz[13] : -phz[13];
        ab += ((outer>>1)&1u)? phz[14] : -phz[14];
        #pragma unroll
        for (int i=0;i<32;i++){
            float al = ab;
            al += (i&1)?      phz[0] : -phz[0];
            al += ((i>>1)&1)? phz[1] : -phz[1];
            al += ((i>>2)&1)? phz[2] : -phz[2];
            al += ((i>>3)&1)? phz[3] : -phz[3];
            al += ((i>>4)&1)? phz[4] : -phz[4];
            float sn,cs; __sincosf(al,&sn,&cs);
            float2 v=a[i];
            a[i]=make_float2(v.x*cs - v.y*sn, v.x*sn + v.y*cs);
        }
        // Ry_{l+1}(f1..f4): targets i bits 1..4
        #pragma unroll
        for (int qq=1;qq<=4;qq++){
            const int bit = 1<<qq;
            const float c=cN[qq], s=sN[qq];
            #pragma unroll
            for (int j=0;j<32;j++){ if (j&bit) continue; ry_pair(a[j],a[j|bit],c,s); }
        }
        // ---- transpose T1 -> T3 for a coalesced store (fix 3x write amplification)
        __syncthreads();
        #pragma unroll
        for (int i=0;i<32;i++) tile[swz((unsigned)i | (t<<5))] = a[i];
        __syncthreads();
        #pragma unroll
        for (int i=0;i<32;i++) a[i] = tile[swz((unsigned)(i&3) | (t<<2) | ((unsigned)(i>>2)<<10))];
        // T3 store: f = (i&3) | (t<<2) | ((i>>2)<<10) | (outer<<13)
        #pragma unroll
        for (int u=0;u<8;u++){
            unsigned fb = (t<<2) | ((unsigned)u<<10) | (outer<<13);
            float4* d4 = (float4*)(sp + fb);
            d4[0]=make_float4(a[4*u+0].x,a[4*u+0].y,a[4*u+1].x,a[4*u+1].y);
            d4[1]=make_float4(a[4*u+2].x,a[4*u+2].y,a[4*u+3].x,a[4*u+3].y);
        }
    } else {
        // measurement: q0: (-1)^{f15^f0}; q1: (-1)^{f14}; q2: (-1)^{f13}
        float s0=0.f, s1=0.f;
        #pragma unroll
        for (int i=0;i<32;i++){
            float pr = a[i].x*a[i].x + a[i].y*a[i].y;
            s1 += pr;
            s0 += (i&1)? -pr : pr;
        }
        float v0 = ((outer>>2)&1u)? -s0 : s0;
        float v1 = ((outer>>1)&1u)? -s1 : s1;
        float v2 = (outer&1u)?      -s1 : s1;
        #pragma unroll
        for (int off=32; off>0; off>>=1){
            v0 += __shfl_down(v0, off);
            v1 += __shfl_down(v1, off);
            v2 += __shfl_down(v2, off);
        }
        const int wv = tid>>6, ln = tid&63;
        if (ln==0){ red[wv][0]=v0; red[wv][1]=v1; red[wv][2]=v2; }
        __syncthreads();
        if (tid<3){
            float s = red[0][tid]+red[1][tid]+red[2][tid]+red[3][tid];
            atomicAdd(&outg[b*3+tid], s);
        }
    }
}

// ---------------- Type-B pass (outer = f bits 10..12)
// CN_l(0->15), Rz_l(f15), Ry_{l+1}(f0,f13,f14,f15), CN_{l+1}(15->14),(14->13), Ry_{l+1}(f5..f9)
__global__ __launch_bounds__(256) void k_B(const float* __restrict__ xg,
                                           const float* __restrict__ pg,
                                           float2* __restrict__ st,
                                           int rzoff, int nxoff)
{
    __shared__ float2 tile[8192];
    __shared__ float cN[16], sN[16];
    __shared__ float snp, csp;
    const int tid = threadIdx.x;
    const int b = blockIdx.x >> 3;
    const unsigned outer = blockIdx.x & 7u;        // f bits 10..12
    if (tid < 16){
        int j=tid, q=15-j;
        float th = 0.5f*(xg[b*16+q]*PI_F + pg[nxoff + q]);
        float s,c; __sincosf(th,&s,&c);
        cN[j]=c; sN[j]=s;
    }
    if (tid==16){ float phi = 0.5f*pg[rzoff + 0]; float s,c; __sincosf(phi,&s,&c); snp=s; csp=c; }
    __syncthreads();
    const unsigned t = tid;
    float2* sp = st + ((size_t)b<<16);
    float2 a[32];
    #pragma unroll
    for (int u=0;u<8;u++){
        unsigned fb = (t<<2) | (outer<<10) | ((unsigned)u<<13);
        const float4* s4 = (const float4*)(sp + fb);
        float4 v0=s4[0], v1=s4[1];
        a[4*u+0]=make_float2(v0.x,v0.y); a[4*u+1]=make_float2(v0.z,v0.w);
        a[4*u+2]=make_float2(v1.x,v1.y); a[4*u+3]=make_float2(v1.z,v1.w);
    }
    // CN_l(0->15): control f0 = i bit0, target f15 = i bit4
    #pragma unroll
    for (int j=0;j<32;j++){ if (j&16) continue; if (j&1){ float2 tm=a[j]; a[j]=a[j|16]; a[j|16]=tm; } }
    // Rz_l(f15)
    #pragma unroll
    for (int j=0;j<32;j++){
        float sn = ((j>>4)&1)? snp : -snp;
        float2 v=a[j];
        a[j]=make_float2(v.x*csp - v.y*sn, v.x*sn + v.y*csp);
    }
    // Ry_{l+1}(f0): target i bit0
    #pragma unroll
    for (int j=0;j<32;j++){ if (j&1)  continue; ry_pair(a[j],a[j|1] ,cN[0] ,sN[0]);  }
    // Ry_{l+1}(f13,f14,f15): targets i bits 2,3,4
    #pragma unroll
    for (int j=0;j<32;j++){ if (j&4)  continue; ry_pair(a[j],a[j|4] ,cN[13],sN[13]); }
    #pragma unroll
    for (int j=0;j<32;j++){ if (j&8)  continue; ry_pair(a[j],a[j|8] ,cN[14],sN[14]); }
    #pragma unroll
    for (int j=0;j<32;j++){ if (j&16) continue; ry_pair(a[j],a[j|16],cN[15],sN[15]); }
    // CN_{l+1}(15->14),(14->13)
    #pragma unroll
    for (int j=0;j<32;j++){ if (j&8) continue; if ((j>>4)&1){ float2 tm=a[j]; a[j]=a[j|8]; a[j|8]=tm; } }
    #pragma unroll
    for (int j=0;j<32;j++){ if (j&4) continue; if ((j>>3)&1){ float2 tm=a[j]; a[j]=a[j|4]; a[j|4]=tm; } }
    // transpose T3 -> T2
    #pragma unroll
    for (int i=0;i<32;i++) tile[swz((unsigned)(i&3) | (t<<2) | ((unsigned)(i>>2)<<10))] = a[i];
    __syncthreads();
    #pragma unroll
    for (int i=0;i<32;i++) a[i] = tile[swz((t&31u) | ((unsigned)i<<5) | ((t>>5)<<10))];
    // T2: f5..9 = i ; f0..4 = t&31 ; f13..15 = t>>5
    #pragma unroll
    for (int qq=0;qq<5;qq++){
        const int bit = 1<<qq;
        const float c=cN[5+qq], s=sN[5+qq];
        #pragma unroll
        for (int j=0;j<32;j++){ if (j&bit) continue; ry_pair(a[j],a[j|bit],c,s); }
    }
    #pragma unroll
    for (int i=0;i<32;i++){
        unsigned f = (t&31u) | ((unsigned)i<<5) | (outer<<10) | ((t>>5)<<13);
        sp[f] = a[i];
    }
}

extern "C" void kernel_launch(void* const* d_in, const int* in_sizes, int n_in,
                              void* d_out, int out_size, void* d_ws, size_t ws_size,
                              hipStream_t stream)
{
    const float* x = (const float*)d_in[0];
    const float* params = (const float*)d_in[1];
    float* out = (float*)d_out;
    float2* st = (float2*)d_ws;
    const int B = in_sizes[0] / 16;

    hipMemsetAsync(d_out, 0, (size_t)out_size*sizeof(float), stream);

    const size_t per = (size_t)65536 * sizeof(float2);   // 512 KB per batch element
    int chunk = (int)(ws_size / per);
    if (chunk > 256) chunk = 256;                        // 128 MB working set -> L3-resident
    if (chunk < 1) chunk = 1;
    if (chunk > B) chunk = B;
    for (int b0=0; b0<B; b0+=chunk){
        const int nb = (B-b0 < chunk) ? (B-b0) : chunk;
        dim3 gr(nb*8), bl(256);
        const float* xb = x + (size_t)b0*16;
        float* ob = out + (size_t)b0*3;
        hipLaunchKernelGGL(k_gen2,  gr, bl, 0, stream, xb, params, st);
        hipLaunchKernelGGL(k_A<1>,  gr, bl, 0, stream, xb, params, st, ob);
        hipLaunchKernelGGL(k_B,     gr, bl, 0, stream, xb, params, st, 48, 64);
        hipLaunchKernelGGL(k_A<2>,  gr, bl, 0, stream, xb, params, st, ob);
    }
}

// Round 5
// 249.183 us; speedup vs baseline: 2.2520x; 1.4398x over previous
//
#include <hip/hip_runtime.h>
#include <hip/hip_bf16.h>

#define PI_F 3.14159265f

// Flat index convention: state.reshape((2,)*16) => qubit q corresponds to
// flat bit j = 15 - q.  Circuit per layer (flat-bit gates):
//   Ry on all flat bits j (angle of qubit 15-j)
//   CNOT chain: (c=15,t=14),(14,13),...,(1,0),(0,15)
//   Rz on all flat bits
// Measurement: <Z_q> q=0,1,2  ->  flat bits 15,14,13.
//
// 3-pass structure (512KB/element state in d_ws, canonical st[f]=amp[f]):
//   P1 k_gen2 (B-type, outer=f10..12, WRITE): chain1 folded into generation
//      (b_pre[j]=f_j^f_{j+1} j=0..13, b_pre[14]=f14^f0^f15, b_pre[15]=f0^f15),
//      Rz1 pointwise, Ry2 targets {0..9,13,14,15}, CN2(15->14),(14->13).
//   P2 k_mid (A-type, outer=f13..15, RW): Ry2(10..12), chain2 targets 12..0,
//      Rz2(f0..14), Ry3(1..4) [T1], Ry3(5..9) [T2], Ry3(10..12) [T3], store.
//      (Ry3{1..12} commute past CN2(0->15)+Rz2(f15): disjoint qubits.)
//   P3 k_fin (B-type, outer=f10..12, READ, no LDS tile): CN2(0->15), Rz2(f15),
//      Ry3{0,13,14,15}, then measurement with CN3 FULLY transported:
//      Z_f15 -> parity(f0..f14); Z_f14 -> f14^f15; Z_f13 -> f13^f14^f15.
//      Rz3 dropped (diagonal, |amp|^2 invariant).
// Chunked at 256 elements (128MB) so intermediate passes are L3-resident.

__device__ __forceinline__ unsigned swz(unsigned l){ return l ^ ((l>>5)&31u); }

__device__ __forceinline__ void ry_pair(float2& A0, float2& A1, float c, float s){
    float2 a0=A0, a1=A1;
    A0 = make_float2(c*a0.x - s*a1.x, c*a0.y - s*a1.y);
    A1 = make_float2(s*a0.x + c*a1.x, s*a0.y + c*a1.y);
}

// ---------------- P1: generate post-chain1 state + Rz1 + Ry2{0..9,13..15} + CN2 front
__global__ __launch_bounds__(256) void k_gen2(const float* __restrict__ xg,
                                              const float* __restrict__ pg,
                                              float2* __restrict__ st)
{
    __shared__ float2 tile[8192];
    __shared__ float cA[16], sA[16], cN[16], sN[16], phz[16];
    const int tid = threadIdx.x;
    const int b = blockIdx.x >> 3;
    const unsigned o = blockIdx.x & 7u;            // f bits 10..12
    if (tid < 16){
        int j = tid, q = 15 - j;
        float th = 0.5f*(xg[b*16+q]*PI_F + pg[q]);           // Ry1
        __sincosf(th, &sA[j], &cA[j]);
    } else if (tid < 32){
        int j = tid-16, q = 15 - j;
        float th = 0.5f*(xg[b*16+q]*PI_F + pg[32+q]);        // Ry2
        __sincosf(th, &sN[j], &cN[j]);
    } else if (tid < 48){
        int j = tid-32, q = 15 - j;
        phz[j] = 0.5f*pg[16+q];                               // Rz1
    }
    __syncthreads();
    const unsigned t = tid;
    // T1 layout: f0..4 = i ; f5..9 = t&31 ; f10..12 = o ; f13..15 = t>>5
    const unsigned f5_9 = t & 31u, f13_15 = t >> 5;
    float base = 1.0f;
    {
        const unsigned hb = f5_9 | (o<<5) | (f13_15<<8);     // bits 0..10 = f5..f15
        #pragma unroll
        for (int j=5;j<=13;j++){
            int v = (int)(((hb>>(j-5)) ^ (hb>>(j-4))) & 1u); // b_pre[j]=f_j^f_{j+1}
            base *= v ? sA[j] : cA[j];
        }
    }
    float phb = 0.0f;
    {
        #pragma unroll
        for (int j=5;j<10;j++)  phb += ((f5_9>>(j-5))&1u)   ? phz[j] : -phz[j];
        #pragma unroll
        for (int j=10;j<13;j++) phb += ((o>>(j-10))&1u)     ? phz[j] : -phz[j];
        #pragma unroll
        for (int j=13;j<16;j++) phb += ((f13_15>>(j-13))&1u)? phz[j] : -phz[j];
    }
    const int f5b  = (int)(t & 1u);
    const int f14b = (int)((t>>6)&1u);
    const int f15b = (int)((t>>7)&1u);
    float2 a[32];
    #pragma unroll
    for (int i=0;i<32;i++){
        const int i0=i&1, i1=(i>>1)&1, i2=(i>>2)&1, i3=(i>>3)&1, i4=(i>>4)&1;
        float pr = base;
        pr *= (i0^i1)? sA[0]:cA[0];
        pr *= (i1^i2)? sA[1]:cA[1];
        pr *= (i2^i3)? sA[2]:cA[2];
        pr *= (i3^i4)? sA[3]:cA[3];
        pr *= (i4^f5b)? sA[4]:cA[4];
        pr *= (f14b^i0^f15b)? sA[14]:cA[14];
        pr *= (i0^f15b)? sA[15]:cA[15];
        float ph = phb;
        ph += i0? phz[0]:-phz[0];
        ph += i1? phz[1]:-phz[1];
        ph += i2? phz[2]:-phz[2];
        ph += i3? phz[3]:-phz[3];
        ph += i4? phz[4]:-phz[4];
        float sn,cs; __sincosf(ph,&sn,&cs);
        a[i] = make_float2(pr*cs, pr*sn);
    }
    // Ry2 targets f0..f4 (i bits 0..4)
    #pragma unroll
    for (int qq=0;qq<5;qq++){
        const int bit=1<<qq;
        const float c=cN[qq], s=sN[qq];
        #pragma unroll
        for (int j=0;j<32;j++){ if (j&bit) continue; ry_pair(a[j],a[j|bit],c,s); }
    }
    // T1 -> T2
    #pragma unroll
    for (int i=0;i<32;i++) tile[swz((unsigned)i | (f5_9<<5) | (f13_15<<10))] = a[i];
    __syncthreads();
    #pragma unroll
    for (int i=0;i<32;i++) a[i] = tile[swz((t&31u) | ((unsigned)i<<5) | ((t>>5)<<10))];
    // T2: f0..4 = t&31 ; f5..9 = i ; f13..15 = t>>5
    #pragma unroll
    for (int qq=0;qq<5;qq++){
        const int bit=1<<qq;
        const float c=cN[5+qq], s=sN[5+qq];
        #pragma unroll
        for (int j=0;j<32;j++){ if (j&bit) continue; ry_pair(a[j],a[j|bit],c,s); }
    }
    // T2 -> T3
    #pragma unroll
    for (int i=0;i<32;i++) tile[swz((t&31u) | ((unsigned)i<<5) | ((t>>5)<<10))] = a[i];
    __syncthreads();
    #pragma unroll
    for (int i=0;i<32;i++) a[i] = tile[swz((unsigned)(i&3) | (t<<2) | ((unsigned)(i>>2)<<10))];
    // T3: f0,f1 = i&3 ; f2..9 = t ; f13..15 = i>>2
    // Ry2 targets f13,f14,f15 = i bits 2,3,4
    #pragma unroll
    for (int j=0;j<32;j++){ if (j&4)  continue; ry_pair(a[j],a[j|4] ,cN[13],sN[13]); }
    #pragma unroll
    for (int j=0;j<32;j++){ if (j&8)  continue; ry_pair(a[j],a[j|8] ,cN[14],sN[14]); }
    #pragma unroll
    for (int j=0;j<32;j++){ if (j&16) continue; ry_pair(a[j],a[j|16],cN[15],sN[15]); }
    // CN2(15->14); CN2(14->13)
    #pragma unroll
    for (int j=0;j<32;j++){ if (j&8) continue; if ((j>>4)&1){ float2 tm=a[j]; a[j]=a[j|8]; a[j|8]=tm; } }
    #pragma unroll
    for (int j=0;j<32;j++){ if (j&4) continue; if ((j>>3)&1){ float2 tm=a[j]; a[j]=a[j|4]; a[j|4]=tm; } }
    float2* sp = st + ((size_t)b<<16);
    #pragma unroll
    for (int u=0;u<8;u++){
        unsigned fb = (t<<2) | (o<<10) | ((unsigned)u<<13);
        float4* d4 = (float4*)(sp + fb);
        d4[0]=make_float4(a[4*u+0].x,a[4*u+0].y,a[4*u+1].x,a[4*u+1].y);
        d4[1]=make_float4(a[4*u+2].x,a[4*u+2].y,a[4*u+3].x,a[4*u+3].y);
    }
}

// ---------------- P2 k_mid (A-type, outer = f13..15, RW):
// Ry2(10..12), chain2 targets 12..0, Rz2(f0..14), Ry3(1..12)
__global__ __launch_bounds__(256) void k_mid(const float* __restrict__ xg,
                                             const float* __restrict__ pg,
                                             float2* __restrict__ st)
{
    __shared__ float2 tile[8192];
    __shared__ float cP[16], sP[16], cN[16], sN[16], phz[16];
    const int tid = threadIdx.x;
    const int b = blockIdx.x >> 3;
    const unsigned outer = blockIdx.x & 7u;        // f bits 13..15
    if (tid < 16){
        int j=tid, q=15-j;
        { float th=0.5f*(xg[b*16+q]*PI_F + pg[32+q]); float s,c; __sincosf(th,&s,&c); cP[j]=c; sP[j]=s; } // Ry2
        { float th=0.5f*(xg[b*16+q]*PI_F + pg[64+q]); float s,c; __sincosf(th,&s,&c); cN[j]=c; sN[j]=s; } // Ry3
        phz[j] = 0.5f*pg[48 + q];                                                                          // Rz2
    }
    __syncthreads();
    const unsigned t = tid;
    float2* sp = st + ((size_t)b<<16);
    float2 a[32];
    // ---- T3 load: f = (i&3) | (t<<2) | ((i>>2)<<10) | (outer<<13)
    #pragma unroll
    for (int u=0;u<8;u++){
        unsigned fb = (t<<2) | ((unsigned)u<<10) | (outer<<13);
        const float4* s4 = (const float4*)(sp + fb);
        float4 v0=s4[0], v1=s4[1];
        a[4*u+0]=make_float2(v0.x,v0.y); a[4*u+1]=make_float2(v0.z,v0.w);
        a[4*u+2]=make_float2(v1.x,v1.y); a[4*u+3]=make_float2(v1.z,v1.w);
    }
    // Ry2(f10,f11,f12): targets i bits 2,3,4
    #pragma unroll
    for (int j=0;j<32;j++){ if (j&4)  continue; ry_pair(a[j],a[j|4] ,cP[10],sP[10]); }
    #pragma unroll
    for (int j=0;j<32;j++){ if (j&8)  continue; ry_pair(a[j],a[j|8] ,cP[11],sP[11]); }
    #pragma unroll
    for (int j=0;j<32;j++){ if (j&16) continue; ry_pair(a[j],a[j|16],cP[12],sP[12]); }
    // CN2(13->12): control f13 = outer bit0 (uniform), target i bit4
    if (outer & 1u){
        #pragma unroll
        for (int j=0;j<32;j++){ if (j&16) continue; float2 tm=a[j]; a[j]=a[j|16]; a[j|16]=tm; }
    }
    // CN2(12->11): control i bit4, target i bit3
    #pragma unroll
    for (int j=0;j<32;j++){ if (j&8) continue; if ((j>>4)&1){ float2 tm=a[j]; a[j]=a[j|8]; a[j|8]=tm; } }
    // CN2(11->10): control i bit3, target i bit2
    #pragma unroll
    for (int j=0;j<32;j++){ if (j&4) continue; if ((j>>3)&1){ float2 tm=a[j]; a[j]=a[j|4]; a[j|4]=tm; } }
    // ---- transpose T3 -> T2
    #pragma unroll
    for (int i=0;i<32;i++) tile[swz((unsigned)(i&3) | (t<<2) | ((unsigned)(i>>2)<<10))] = a[i];
    __syncthreads();
    #pragma unroll
    for (int i=0;i<32;i++) a[i] = tile[swz((t&31u) | ((unsigned)i<<5) | ((t>>5)<<10))];
    // T2: f5..9 = i; f0..4 = t&31; f10..12 = t>>5
    // CN2(10->9): control f10 = (t>>5)&1 (fixed), target i bit4
    if ((t>>5)&1u){
        #pragma unroll
        for (int j=0;j<32;j++){ if (j&16) continue; float2 tm=a[j]; a[j]=a[j|16]; a[j|16]=tm; }
    }
    // CN2(9->8),(8->7),(7->6),(6->5)
    #pragma unroll
    for (int qq=3;qq>=0;qq--){
        const int bit = 1<<qq;
        #pragma unroll
        for (int j=0;j<32;j++){ if (j&bit) continue; if ((j>>(qq+1))&1){ float2 tm=a[j]; a[j]=a[j|bit]; a[j|bit]=tm; } }
    }
    // ---- transpose T2 -> T1
    #pragma unroll
    for (int i=0;i<32;i++) tile[swz((t&31u) | ((unsigned)i<<5) | ((t>>5)<<10))] = a[i];
    __syncthreads();
    #pragma unroll
    for (int i=0;i<32;i++) a[i] = tile[swz((unsigned)i | (t<<5))];
    // T1: f0..4 = i; f5..12 = t; f13..15 = outer
    // CN2(5->4): control f5 = t bit0, target i bit4
    if (t & 1u){
        #pragma unroll
        for (int j=0;j<32;j++){ if (j&16) continue; float2 tm=a[j]; a[j]=a[j|16]; a[j|16]=tm; }
    }
    // CN2(4->3),(3->2),(2->1),(1->0)
    #pragma unroll
    for (int qq=3;qq>=0;qq--){
        const int bit = 1<<qq;
        #pragma unroll
        for (int j=0;j<32;j++){ if (j&bit) continue; if ((j>>(qq+1))&1){ float2 tm=a[j]; a[j]=a[j|bit]; a[j|bit]=tm; } }
    }
    // Rz2 on flat bits 0..14 (f15 deferred to k_fin, after CN2(0->15))
    float ab = 0.0f;
    #pragma unroll
    for (int j=5;j<13;j++) ab += ((t>>(j-5))&1u)? phz[j] : -phz[j];
    ab += (outer&1u)?      phz[13] : -phz[13];
    ab += ((outer>>1)&1u)? phz[14] : -phz[14];
    #pragma unroll
    for (int i=0;i<32;i++){
        float al = ab;
        al += (i&1)?      phz[0] : -phz[0];
        al += ((i>>1)&1)? phz[1] : -phz[1];
        al += ((i>>2)&1)? phz[2] : -phz[2];
        al += ((i>>3)&1)? phz[3] : -phz[3];
        al += ((i>>4)&1)? phz[4] : -phz[4];
        float sn,cs; __sincosf(al,&sn,&cs);
        float2 v=a[i];
        a[i]=make_float2(v.x*cs - v.y*sn, v.x*sn + v.y*cs);
    }
    // Ry3(f1..f4): targets i bits 1..4   (Ry3{1..12} commute past CN2(0->15))
    #pragma unroll
    for (int qq=1;qq<=4;qq++){
        const int bit = 1<<qq;
        const float c=cN[qq], s=sN[qq];
        #pragma unroll
        for (int j=0;j<32;j++){ if (j&bit) continue; ry_pair(a[j],a[j|bit],c,s); }
    }
    // ---- transpose T1 -> T2: Ry3(f5..f9)
    __syncthreads();
    #pragma unroll
    for (int i=0;i<32;i++) tile[swz((unsigned)i | (t<<5))] = a[i];
    __syncthreads();
    #pragma unroll
    for (int i=0;i<32;i++) a[i] = tile[swz((t&31u) | ((unsigned)i<<5) | ((t>>5)<<10))];
    #pragma unroll
    for (int qq=0;qq<5;qq++){
        const int bit = 1<<qq;
        const float c=cN[5+qq], s=sN[5+qq];
        #pragma unroll
        for (int j=0;j<32;j++){ if (j&bit) continue; ry_pair(a[j],a[j|bit],c,s); }
    }
    // ---- transpose T2 -> T3: Ry3(f10..f12) + coalesced store
    #pragma unroll
    for (int i=0;i<32;i++) tile[swz((t&31u) | ((unsigned)i<<5) | ((t>>5)<<10))] = a[i];
    __syncthreads();
    #pragma unroll
    for (int i=0;i<32;i++) a[i] = tile[swz((unsigned)(i&3) | (t<<2) | ((unsigned)(i>>2)<<10))];
    // T3: f0,f1 = i&3; f2..9 = t; f10..12 = i>>2
    #pragma unroll
    for (int j=0;j<32;j++){ if (j&4)  continue; ry_pair(a[j],a[j|4] ,cN[10],sN[10]); }
    #pragma unroll
    for (int j=0;j<32;j++){ if (j&8)  continue; ry_pair(a[j],a[j|8] ,cN[11],sN[11]); }
    #pragma unroll
    for (int j=0;j<32;j++){ if (j&16) continue; ry_pair(a[j],a[j|16],cN[12],sN[12]); }
    #pragma unroll
    for (int u=0;u<8;u++){
        unsigned fb = (t<<2) | ((unsigned)u<<10) | (outer<<13);
        float4* d4 = (float4*)(sp + fb);
        d4[0]=make_float4(a[4*u+0].x,a[4*u+0].y,a[4*u+1].x,a[4*u+1].y);
        d4[1]=make_float4(a[4*u+2].x,a[4*u+2].y,a[4*u+3].x,a[4*u+3].y);
    }
}

// ---------------- P3 k_fin (B-type, outer = f10..12, READ, no LDS tile):
// CN2(0->15), Rz2(f15), Ry3{0,13,14,15}, measurement with CN3 transported:
//   <Z_q0> mask = parity(f0..f14); <Z_q1> = f14^f15; <Z_q2> = f13^f14^f15.
__global__ __launch_bounds__(256) void k_fin(const float* __restrict__ xg,
                                             const float* __restrict__ pg,
                                             const float2* __restrict__ st,
                                             float* __restrict__ outg)
{
    __shared__ float cN[16], sN[16];
    __shared__ float snp, csp;
    __shared__ float red[4][3];
    const int tid = threadIdx.x;
    const int b = blockIdx.x >> 3;
    const unsigned outer = blockIdx.x & 7u;        // f bits 10..12
    if (tid < 16){
        int j=tid, q=15-j;
        float th = 0.5f*(xg[b*16+q]*PI_F + pg[64 + q]);      // Ry3
        float s,c; __sincosf(th,&s,&c);
        cN[j]=c; sN[j]=s;
    }
    if (tid==16){ float phi = 0.5f*pg[48 + 0]; float s,c; __sincosf(phi,&s,&c); snp=s; csp=c; }  // Rz2(f15)=qubit0
    __syncthreads();
    const unsigned t = tid;
    const float2* sp = st + ((size_t)b<<16);
    float2 a[32];
    // T3 load (B-type): f = (i&3) | (t<<2) | (outer<<10) | ((i>>2)<<13)
    #pragma unroll
    for (int u=0;u<8;u++){
        unsigned fb = (t<<2) | (outer<<10) | ((unsigned)u<<13);
        const float4* s4 = (const float4*)(sp + fb);
        float4 v0=s4[0], v1=s4[1];
        a[4*u+0]=make_float2(v0.x,v0.y); a[4*u+1]=make_float2(v0.z,v0.w);
        a[4*u+2]=make_float2(v1.x,v1.y); a[4*u+3]=make_float2(v1.z,v1.w);
    }
    // CN2(0->15): control f0 = i bit0, target f15 = i bit4
    #pragma unroll
    for (int j=0;j<32;j++){ if (j&16) continue; if (j&1){ float2 tm=a[j]; a[j]=a[j|16]; a[j|16]=tm; } }
    // Rz2(f15): phase +-phi by i bit4
    #pragma unroll
    for (int j=0;j<32;j++){
        float sn = ((j>>4)&1)? snp : -snp;
        float2 v=a[j];
        a[j]=make_float2(v.x*csp - v.y*sn, v.x*sn + v.y*csp);
    }
    // Ry3(f0): i bit0 ; Ry3(f13,f14,f15): i bits 2,3,4
    #pragma unroll
    for (int j=0;j<32;j++){ if (j&1)  continue; ry_pair(a[j],a[j|1] ,cN[0] ,sN[0]);  }
    #pragma unroll
    for (int j=0;j<32;j++){ if (j&4)  continue; ry_pair(a[j],a[j|4] ,cN[13],sN[13]); }
    #pragma unroll
    for (int j=0;j<32;j++){ if (j&8)  continue; ry_pair(a[j],a[j|8] ,cN[14],sN[14]); }
    #pragma unroll
    for (int j=0;j<32;j++){ if (j&16) continue; ry_pair(a[j],a[j|16],cN[15],sN[15]); }
    // measurement sums; f0=i0, f1=i1, f2..9=t, f10..12=outer, f13=i2, f14=i3, f15=i4
    const int pto = (__popc(t) + __popc(outer)) & 1;   // parity(f2..f12)
    float v0=0.f, v1=0.f, v2=0.f;
    #pragma unroll
    for (int i=0;i<32;i++){
        const int i0=i&1, i1=(i>>1)&1, i2=(i>>2)&1, i3=(i>>3)&1, i4=(i>>4)&1;
        const float pr = a[i].x*a[i].x + a[i].y*a[i].y;
        v0 += (i0^i1^i2^i3^pto)? -pr : pr;   // parity(f0..f14)
        v1 += (i3^i4)?           -pr : pr;   // f14^f15
        v2 += (i2^i3^i4)?        -pr : pr;   // f13^f14^f15
    }
    #pragma unroll
    for (int off=32; off>0; off>>=1){
        v0 += __shfl_down(v0, off);
        v1 += __shfl_down(v1, off);
        v2 += __shfl_down(v2, off);
    }
    const int wv = tid>>6, ln = tid&63;
    if (ln==0){ red[wv][0]=v0; red[wv][1]=v1; red[wv][2]=v2; }
    __syncthreads();
    if (tid<3){
        float s = red[0][tid]+red[1][tid]+red[2][tid]+red[3][tid];
        atomicAdd(&outg[b*3+tid], s);
    }
}

extern "C" void kernel_launch(void* const* d_in, const int* in_sizes, int n_in,
                              void* d_out, int out_size, void* d_ws, size_t ws_size,
                              hipStream_t stream)
{
    const float* x = (const float*)d_in[0];
    const float* params = (const float*)d_in[1];
    float* out = (float*)d_out;
    float2* st = (float2*)d_ws;
    const int B = in_sizes[0] / 16;

    hipMemsetAsync(d_out, 0, (size_t)out_size*sizeof(float), stream);

    const size_t per = (size_t)65536 * sizeof(float2);   // 512 KB per batch element
    int chunk = (int)(ws_size / per);
    if (chunk > 256) chunk = 256;                        // 128 MB working set -> L3-resident
    if (chunk < 1) chunk = 1;
    if (chunk > B) chunk = B;
    for (int b0=0; b0<B; b0+=chunk){
        const int nb = (B-b0 < chunk) ? (B-b0) : chunk;
        dim3 gr(nb*8), bl(256);
        const float* xb = x + (size_t)b0*16;
        float* ob = out + (size_t)b0*3;
        hipLaunchKernelGGL(k_gen2, gr, bl, 0, stream, xb, params, st);
        hipLaunchKernelGGL(k_mid,  gr, bl, 0, stream, xb, params, st);
        hipLaunchKernelGGL(k_fin,  gr, bl, 0, stream, xb, params, st, ob);
    }
}